// Round 14
// baseline (166.552 us; speedup 1.0000x reference)
//
#include <hip/hip_runtime.h>

typedef __bf16 bf16_t;
typedef __bf16 bf16x8 __attribute__((ext_vector_type(8)));
typedef float f32x4 __attribute__((ext_vector_type(4)));
typedef unsigned int u32;

#define MFMA16(A, B, C) __builtin_amdgcn_mfma_f32_16x16x32_bf16(A, B, C, 0, 0, 0)

static constexpr int N_CODE = 8192;

// ---- workspace layout (bytes), de-aliased ----
static constexpr size_t OFF_B1   = 0;                       // 393216
static constexpr size_t OFF_B2   = OFF_B1 + 393216;         // 393216
static constexpr size_t OFF_B3   = OFF_B2 + 393216;         // 131072
static constexpr size_t OFF_BV   = OFF_B3 + 131072;         // 131072
static constexpr size_t OFF_BIAS = OFF_BV + 131072;         // 8192
static constexpr size_t OFF_U1   = OFF_BIAS + 8192;         // 1024
static constexpr size_t OFF_U23  = OFF_U1 + 1024;           // 1024
static constexpr size_t OFF_CNT  = OFF_U23 + 1024;          // 256
static constexpr size_t OFF_IDXS = OFF_CNT + 256;           // 32768
static constexpr size_t OFF_IDXM = OFF_IDXS + 32768;        // 32768
static constexpr size_t OFF_GXC  = OFF_IDXM + 32768;        // 12582912
static constexpr size_t OFF_GHC  = OFF_GXC + 12582912;      // 12582912
static constexpr size_t OFF_G3C  = OFF_GHC + 12582912;      // 4194304
static constexpr size_t OFF_VT   = OFF_G3C + 4194304;       // 4194304
static constexpr size_t OFF_KP   = OFF_VT + 4194304;        // 2097152
static constexpr size_t OFF_VP   = OFF_KP + 2097152;        // 4194304
static constexpr size_t OFF_PML  = OFF_VP + 4194304;        // 524288
static constexpr size_t OFF_PO   = OFF_PML + 524288;        // ksplit*4194304 (<=33.5MB)
// NOTE (round 9): NO device-scope fences / cross-block done-counters (+60us XCD L2 writeback).
// NOTE (round 11): NO register-staged K/V tiles in attn (spills -> 120MB scratch writes).
//                  This round uses global_load_lds instead: zero VGPR cost, linear LDS dest.

__device__ __forceinline__ unsigned umap_f(float f) {
    unsigned u = __float_as_uint(f);
    return (u & 0x80000000u) ? ~u : (u | 0x80000000u);   // monotone: larger float -> larger uint
}
__device__ __forceinline__ float unmap_f(unsigned u) {
    unsigned b = (u & 0x80000000u) ? (u & 0x7fffffffu) : ~u;
    return __uint_as_float(b);
}

__device__ __forceinline__ void gload16(const bf16_t* g, bf16_t* l) {
    // async global->LDS, 16B per lane; LDS dest = wave-uniform base + lane*16
    __builtin_amdgcn_global_load_lds(
        (const __attribute__((address_space(1))) u32*)g,
        (__attribute__((address_space(3))) u32*)l,
        16, 0, 0);
}

// ---- fused: block 0 = compaction scan (shfl-based); blocks 1..128 = weight pack ----
__global__ __launch_bounds__(1024)
void tl_prep_scan(const float* __restrict__ W_ih, const float* __restrict__ W_hh,
                  const float* __restrict__ Wq, const float* __restrict__ Wk,
                  const float* __restrict__ Wv,
                  const float* __restrict__ b_ih, const float* __restrict__ b_hh,
                  const float* __restrict__ bq, const float* __restrict__ bk,
                  const float* __restrict__ bv,
                  const int* __restrict__ divided,
                  bf16_t* __restrict__ B1p, bf16_t* __restrict__ B2p,
                  bf16_t* __restrict__ B3p, bf16_t* __restrict__ BVp,
                  float* __restrict__ biases,
                  unsigned* __restrict__ u1, unsigned* __restrict__ u23,
                  int* __restrict__ idxS, int* __restrict__ idxM1, int* __restrict__ counts)
{
    int t = threadIdx.x;
    if (blockIdx.x == 0) {
        __shared__ int w1[16], w23[16];
        int lane = t & 63, wv = t >> 6;
        int d[8]; int c1 = 0, c23 = 0;
#pragma unroll
        for (int i = 0; i < 8; ++i) {
            d[i] = divided[t*8 + i];
            c1  += (d[i] == 0);
            c23 += (d[i] != 0);
        }
        int s1v = c1, s23v = c23;
#pragma unroll
        for (int off = 1; off < 64; off <<= 1) {
            int a1  = __shfl_up(s1v,  off, 64);
            int a23 = __shfl_up(s23v, off, 64);
            if (lane >= off) { s1v += a1; s23v += a23; }
        }
        if (lane == 63) { w1[wv] = s1v; w23[wv] = s23v; }
        __syncthreads();
        if (wv == 0 && lane < 16) {
            int v1 = w1[lane], v23 = w23[lane];
#pragma unroll
            for (int off = 1; off < 16; off <<= 1) {
                int a1  = __shfl_up(v1,  off, 16);
                int a23 = __shfl_up(v23, off, 16);
                if (lane >= off) { v1 += a1; v23 += a23; }
            }
            w1[lane] = v1; w23[lane] = v23;
        }
        __syncthreads();
        int base1  = (wv > 0) ? w1[wv-1]  : 0;
        int base23 = (wv > 0) ? w23[wv-1] : 0;
        int o1  = base1  + s1v  - c1;
        int o23 = base23 + s23v - c23;
#pragma unroll
        for (int i = 0; i < 8; ++i) {
            if (d[i] == 0) idxM1[o1++] = t*8 + i;
            else           idxS[o23++] = t*8 + i;
        }
        if (t == 1023) { counts[0] = w23[15]; counts[1] = w1[15]; }
        return;
    }
    int idx = (blockIdx.x - 1) * 1024 + t;
    const int T1 = 196608, T2 = 196608, T3 = 65536, T4 = 65536;
    for (int i = idx; i < T1 + T2 + T3 + T4; i += 128 * 1024) {
        int which, l;
        if (i < T1)                { which = 0; l = i; }
        else if (i < T1 + T2)      { which = 1; l = i - T1; }
        else if (i < T1 + T2 + T3) { which = 2; l = i - T1 - T2; }
        else                       { which = 3; l = i - T1 - T2 - T3; }
        int j = l & 7, lane = (l >> 3) & 63, kk = (l >> 9) & 7, n16 = l >> 12;
        int k = kk*32 + (lane >> 4)*8 + j;      // K index 0..255
        int n = n16*16 + (lane & 15);           // output column
        if (which == 0)      B1p[l] = (bf16_t)W_ih[n*256 + k];
        else if (which == 1) B2p[l] = (bf16_t)W_hh[n*256 + k];
        else if (which == 2) B3p[l] = (bf16_t)((n < 128) ? Wq[k*128 + n] : Wk[k*128 + (n - 128)]);
        else                 BVp[l] = (bf16_t)Wv[k*256 + n];
    }
    if (idx < 768)       biases[idx] = b_ih[idx];
    else if (idx < 1536) biases[idx] = b_hh[idx - 768];
    else if (idx < 1792) { int q = idx - 1536; biases[idx] = (q < 128) ? bq[q] : bk[q - 128]; }
    else if (idx < 2048) biases[idx] = bv[idx - 1792];
    if (idx < 256) { u1[idx] = 0x007FFFFFu; u23[idx] = 0x007FFFFFu; }  // umap(-inf)
}

__device__ __forceinline__ bf16x8 load_cvt8(const float* p) {
    f32x4 a = *(const f32x4*)p;
    f32x4 b = *(const f32x4*)(p + 4);
    bf16x8 r;
#pragma unroll
    for (int j = 0; j < 4; ++j) { r[j] = (bf16_t)a[j]; r[j+4] = (bf16_t)b[j]; }
    return r;
}

// ---- quad gathered GEMM, WIDE: each wave owns 64 cols (4 n-frags) ----
__global__ __launch_bounds__(256, 2)
void tl_gemm_quad(const float* __restrict__ m_emb, const float* __restrict__ hidden,
                  const float* __restrict__ ddi, const float* __restrict__ unrel,
                  const int* __restrict__ divided,
                  const bf16_t* __restrict__ B1p, const bf16_t* __restrict__ B2p,
                  const bf16_t* __restrict__ B3p, const bf16_t* __restrict__ BVp,
                  const float* __restrict__ biases,
                  bf16_t* __restrict__ gxc, bf16_t* __restrict__ ghc,
                  bf16_t* __restrict__ G3c, bf16_t* __restrict__ Vt,
                  const int* __restrict__ idxM1, const int* __restrict__ idxS,
                  const int* __restrict__ counts)
{
    int y = blockIdx.y;
    const float* A0; const float* A1 = nullptr; int mode = 0;
    const bf16_t* Bp; const float* bias; bf16_t* C; int NOUT; int y0;
    const int* gidx; int cnt;
    if (y < 3)       { A0 = m_emb;  gidx = idxM1; cnt = counts[1]; Bp = B1p; bias = biases;        C = gxc; NOUT = 768; y0 = y; }
    else if (y < 6)  { A0 = hidden; gidx = idxM1; cnt = counts[1]; Bp = B2p; bias = biases + 768;  C = ghc; NOUT = 768; y0 = y - 3; }
    else if (y == 6) { A0 = ddi; A1 = unrel; mode = 2;
                       gidx = idxS;  cnt = counts[0]; Bp = B3p; bias = biases + 1536; C = G3c; NOUT = 256; y0 = 0; }
    else             { A0 = m_emb;  gidx = idxS;  cnt = counts[0]; Bp = BVp; bias = biases + 1792; C = Vt;  NOUT = 256; y0 = 0; }

    int m0 = blockIdx.x * 64;
    if (m0 >= cnt) return;
    int lane = threadIdx.x & 63;
    int w    = threadIdx.x >> 6;
    int rlo = lane & 15, khi = lane >> 4;
    int nbase = y0 * 256 + w * 64;

    const float* arow[4];
#pragma unroll
    for (int m = 0; m < 4; ++m) {
        int row = m0 + m*16 + rlo;
        int src = gidx[(row < cnt) ? row : 0];
        const float* base = A0;
        if (mode == 2) base = (divided[src] == 1) ? A0 : A1;
        arow[m] = base + (size_t)src * 256;
    }
    f32x4 acc[4][4] = {};
    const bf16_t* bptr = Bp + (size_t)(nbase >> 4) * 4096 + lane * 8;
#pragma unroll
    for (int kk = 0; kk < 8; ++kk) {
        bf16x8 bfrag[4];
#pragma unroll
        for (int nf = 0; nf < 4; ++nf)
            bfrag[nf] = *(const bf16x8*)(bptr + nf * 4096 + kk * 512);
#pragma unroll
        for (int m = 0; m < 4; ++m) {
            bf16x8 afrag = load_cvt8(arow[m] + kk*32 + khi*8);
#pragma unroll
            for (int nf = 0; nf < 4; ++nf)
                acc[m][nf] = MFMA16(afrag, bfrag[nf], acc[m][nf]);
        }
    }
#pragma unroll
    for (int nf = 0; nf < 4; ++nf) {
        int col = nbase + nf*16 + rlo;
        float b = bias[col];
#pragma unroll
        for (int m = 0; m < 4; ++m)
#pragma unroll
            for (int r = 0; r < 4; ++r) {
                int row = m0 + m*16 + khi*4 + r;
                C[(size_t)row * NOUT + col] = (bf16_t)(acc[m][nf][r] + b);
            }
    }
}

// ---- fused gru (blocks 0..1023) + pack (blocks 1024..3071) ----
__global__ __launch_bounds__(256)
void tl_gru_pack(const bf16_t* __restrict__ gx, const bf16_t* __restrict__ gh,
                 const float* __restrict__ hidden,
                 const int* __restrict__ idxM1, const int* __restrict__ counts,
                 float* __restrict__ h_new, unsigned* __restrict__ u1,
                 const bf16_t* __restrict__ G3c, const bf16_t* __restrict__ Vt,
                 bf16_t* __restrict__ Kp, bf16_t* __restrict__ Vp)
{
    if (blockIdx.x < 1024) {
        int nM1 = counts[1];
        int i0 = blockIdx.x * 8;
        if (i0 >= nM1) return;
        int j = threadIdx.x;
        int iend = (i0 + 8 < nM1) ? i0 + 8 : nM1;
        float cmax = -1e30f;
        for (int i = i0; i < iend; ++i) {
            int row = idxM1[i];
            float xr = (float)gx[(size_t)i*768 + j];
            float xz = (float)gx[(size_t)i*768 + 256 + j];
            float xn = (float)gx[(size_t)i*768 + 512 + j];
            float hr = (float)gh[(size_t)i*768 + j];
            float hz = (float)gh[(size_t)i*768 + 256 + j];
            float hn = (float)gh[(size_t)i*768 + 512 + j];
            float h  = hidden[(size_t)row*256 + j];
            float r = 1.f/(1.f + __expf(-(xr + hr)));
            float z = 1.f/(1.f + __expf(-(xz + hz)));
            float n = tanhf(xn + r*hn);
            float hg = (1.f - z)*n + z*h;
            h_new[(size_t)row*256 + j] = hg;
            cmax = fmaxf(cmax, hg);
        }
        atomicMax(&u1[j], umap_f(cmax));
        return;
    }
    int nS = counts[0];
    int nT = (nS + 63) >> 6;
    int r = (blockIdx.x - 1024) * 4 + (threadIdx.x >> 6);
    if (r >= nT * 64) return;
    int t = threadIdx.x & 63;
    bool valid = r < nS;
    if (t < 16) {                 // K b-frags: [kt][ks4][nf4][lane][8]
        bf16x8 v = {};
        if (valid) v = *(const bf16x8*)(G3c + (size_t)r*256 + 128 + t*8);
        int kt = r >> 6, keyin = r & 63;
        int ks = t >> 2, lhi = t & 3, nf = keyin >> 4;
        int lane = (lhi << 4) | (keyin & 15);
        *(bf16x8*)(Kp + ((((size_t)kt*4 + ks)*4 + nf)*64 + lane)*8) = v;
    } else if (t < 48) {          // V b-frags: [kt][ks2][nf16][lane][8]
        int j8 = t - 16;
        int d0 = j8 * 8;
        bf16x8 v = {};
        if (valid) v = *(const bf16x8*)(Vt + (size_t)r*256 + d0);
        int kt = r >> 6, ks2 = (r >> 5) & 1, jj = r & 7, lhi = (r >> 3) & 3;
#pragma unroll
        for (int q = 0; q < 8; ++q) {
            int d = d0 + q;
            int nf = d >> 4;
            int lane = (lhi << 4) | (d & 15);
            Vp[((((size_t)kt*2 + ks2)*16 + nf)*64 + lane)*8 + jj] = v[q];
        }
    }
}

// ---- flash attention: R5 per-wave math + global_load_lds double-buffered K/V staging ----
// Per 64-key tile: 48KB staged ONCE per block (vs 4x redundant per-wave L2 reads).
// Prefetch for tile kt+1 issued right after the barrier; __syncthreads' vmcnt(0) drain
// is the completion wait. LDS dest is linear (packed layout already lane-ordered).
__global__ __launch_bounds__(256)
void tl_attn(const bf16_t* __restrict__ G3c, const bf16_t* __restrict__ Kp,
             const bf16_t* __restrict__ Vp, const int* __restrict__ counts,
             int ksplit, float* __restrict__ pml, bf16_t* __restrict__ pO)
{
    int nS = counts[0];
    int nT = (nS + 63) >> 6;
    int qt = blockIdx.y;
    if (qt >= nT) return;
    int c = blockIdx.x;
    int kt0 = (nT * c) / ksplit, kt1 = (nT * (c + 1)) / ksplit;

    int tid  = threadIdx.x;
    int lane = tid & 63;
    int w    = tid >> 6;
    int rlo = lane & 15, khi = lane >> 4;
    int qbase = qt * 64 + w * 16;

    __shared__ __align__(16) bf16_t KV[2][24576];       // 2 x 48KB: K [0,8192) | V [8192,24576)
    __shared__ __align__(16) bf16_t P_lds[4][16][72];   // per-wave private strip

    bf16x8 aQ[4];
    const bf16_t* qrow = G3c + (size_t)(qbase + rlo) * 256 + khi * 8;
#pragma unroll
    for (int ks = 0; ks < 4; ++ks) aQ[ks] = *(const bf16x8*)(qrow + ks * 32);

    float m_run[4], l_run[4];
#pragma unroll
    for (int r = 0; r < 4; ++r) { m_run[r] = -1e30f; l_run[r] = 0.f; }
    f32x4 O[16];
#pragma unroll
    for (int i = 0; i < 16; ++i) O[i] = (f32x4){0.f, 0.f, 0.f, 0.f};

    const float scale = 0.088388347648318447f;   // 1/sqrt(128)

    // prologue: stage first tile into KV[0]
    int cur = 0;
    if (kt0 < kt1) {
        const bf16_t* gK = Kp + (size_t)kt0 * 8192;
        const bf16_t* gV = Vp + (size_t)kt0 * 16384;
#pragma unroll
        for (int i = 0; i < 4; ++i) gload16(gK + i*2048 + tid*8, &KV[0][i*2048 + w*512]);
#pragma unroll
        for (int i = 0; i < 8; ++i) gload16(gV + i*2048 + tid*8, &KV[0][8192 + i*2048 + w*512]);
    }

    for (int kt = kt0; kt < kt1; ++kt) {
        __syncthreads();   // drains in-flight global_load_lds into KV[cur] (vmcnt(0) + barrier)
        // early-issue next tile into the other buffer; latency hides under this tile's compute
        if (kt + 1 < kt1) {
            const bf16_t* gK = Kp + (size_t)(kt+1) * 8192;
            const bf16_t* gV = Vp + (size_t)(kt+1) * 16384;
            bf16_t* nb = KV[cur ^ 1];
#pragma unroll
            for (int i = 0; i < 4; ++i) gload16(gK + i*2048 + tid*8, nb + i*2048 + w*512);
#pragma unroll
            for (int i = 0; i < 8; ++i) gload16(gV + i*2048 + tid*8, nb + 8192 + i*2048 + w*512);
        }
        const bf16_t* kvb = KV[cur];
        // ---- compute tile kt from LDS (byte-identical math to round-5 form) ----
        f32x4 s[4] = {};
#pragma unroll
        for (int ks = 0; ks < 4; ++ks) {
            const bf16_t* kp = kvb + ks*2048 + lane*8;
#pragma unroll
            for (int nf = 0; nf < 4; ++nf) {
                bf16x8 bK = *(const bf16x8*)(kp + nf * 512);
                s[nf] = MFMA16(aQ[ks], bK, s[nf]);
            }
        }
        int kbase = kt * 64;
#pragma unroll
        for (int nf = 0; nf < 4; ++nf) {
            bool valid = (kbase + nf*16 + rlo) < nS;
#pragma unroll
            for (int r = 0; r < 4; ++r) {
                float v = s[nf][r] * scale;
                s[nf][r] = valid ? v : -1e30f;
            }
        }
        float pm[4];
#pragma unroll
        for (int r = 0; r < 4; ++r)
            pm[r] = fmaxf(fmaxf(s[0][r], s[1][r]), fmaxf(s[2][r], s[3][r]));
#pragma unroll
        for (int off = 1; off < 16; off <<= 1)
#pragma unroll
            for (int r = 0; r < 4; ++r) pm[r] = fmaxf(pm[r], __shfl_xor(pm[r], off, 64));

        float mn[4], sc[4], rs[4];
#pragma unroll
        for (int r = 0; r < 4; ++r) {
            mn[r] = fmaxf(m_run[r], pm[r]);
            sc[r] = __expf(m_run[r] - mn[r]);
            m_run[r] = mn[r];
            rs[r] = 0.f;
        }
#pragma unroll
        for (int nf = 0; nf < 4; ++nf)
#pragma unroll
            for (int r = 0; r < 4; ++r) {
                float p = __expf(s[nf][r] - mn[r]);
                s[nf][r] = p;
                rs[r] += p;
            }
#pragma unroll
        for (int off = 1; off < 16; off <<= 1)
#pragma unroll
            for (int r = 0; r < 4; ++r) rs[r] += __shfl_xor(rs[r], off, 64);
#pragma unroll
        for (int r = 0; r < 4; ++r) l_run[r] = l_run[r]*sc[r] + rs[r];
#pragma unroll
        for (int nf = 0; nf < 16; ++nf)
#pragma unroll
            for (int r = 0; r < 4; ++r) O[nf][r] *= sc[r];
        // P -> per-wave LDS strip, read back in a-frag layout (in-wave dep, no barrier needed)
#pragma unroll
        for (int nf = 0; nf < 4; ++nf)
#pragma unroll
            for (int r = 0; r < 4; ++r)
                P_lds[w][khi*4 + r][nf*16 + rlo] = (bf16_t)s[nf][r];
#pragma unroll
        for (int ks2 = 0; ks2 < 2; ++ks2) {
            bf16x8 pa = *(const bf16x8*)&P_lds[w][rlo][ks2*32 + khi*8];
            const bf16_t* vp = kvb + 8192 + ks2*8192 + lane*8;
#pragma unroll
            for (int nf = 0; nf < 16; ++nf) {
                bf16x8 bV = *(const bf16x8*)(vp + nf * 512);
                O[nf] = MFMA16(pa, bV, O[nf]);
            }
        }
        cur ^= 1;
    }
    if (rlo == 0) {
#pragma unroll
        for (int r = 0; r < 4; ++r) {
            int qc = qbase + khi*4 + r;
            pml[((size_t)c*N_CODE + qc)*2 + 0] = m_run[r];
            pml[((size_t)c*N_CODE + qc)*2 + 1] = l_run[r];
        }
    }
#pragma unroll
    for (int nf = 0; nf < 16; ++nf) {
        int d = nf*16 + rlo;
#pragma unroll
        for (int r = 0; r < 4; ++r) {
            int qc = qbase + khi*4 + r;
            pO[((size_t)c*N_CODE + qc)*256 + d] = (bf16_t)O[nf][r];
        }
    }
}

// ---- merge key-split partials, VECTORIZED ----
template<int KS>
__global__ __launch_bounds__(256)
void tl_merge_t(const bf16_t* __restrict__ pO, const float* __restrict__ pml,
                const int* __restrict__ idxS, const int* __restrict__ counts,
                float* __restrict__ h_new, unsigned* __restrict__ u23)
{
    int nS = counts[0];
    int i0 = blockIdx.x * 8;
    if (i0 >= nS) return;
    int tid = threadIdx.x;
    int qi = tid >> 5;
    int j8 = tid & 31;
    int q  = i0 + qi;

    __shared__ unsigned smax[256];
    smax[tid] = 0x007FFFFFu;      // umap(-inf)
    __syncthreads();

    if (q < nS) {
        float m = -1e30f;
#pragma unroll
        for (int cc = 0; cc < KS; ++cc)
            m = fmaxf(m, pml[((size_t)cc*N_CODE + q)*2 + 0]);
        float e[KS]; float l = 0.f;
#pragma unroll
        for (int cc = 0; cc < KS; ++cc) {
            e[cc] = __expf(pml[((size_t)cc*N_CODE + q)*2 + 0] - m);
            l += pml[((size_t)cc*N_CODE + q)*2 + 1] * e[cc];
        }
        float acc[8] = {};
#pragma unroll
        for (int cc = 0; cc < KS; ++cc) {
            bf16x8 v = *(const bf16x8*)(pO + ((size_t)cc*N_CODE + q)*256 + j8*8);
#pragma unroll
            for (int k = 0; k < 8; ++k) acc[k] += (float)v[k] * e[cc];
        }
        float linv = 1.f / fmaxf(l, 1e-30f);
        f32x4 o0, o1;
#pragma unroll
        for (int k = 0; k < 8; ++k) {
            float val = tanhf(acc[k] * linv);
            if (k < 4) o0[k] = val; else o1[k-4] = val;
            atomicMax(&smax[j8*8 + k], umap_f(val));   // LDS atomic (block-local)
        }
        float* dst = h_new + (size_t)idxS[q]*256 + j8*8;
        *(f32x4*)dst = o0;
        *(f32x4*)(dst + 4) = o1;
    }
    __syncthreads();
    atomicMax(&u23[tid], smax[tid]);   // one global atomic per column per block
}

__global__ void tl_final(const unsigned* __restrict__ u1, const unsigned* __restrict__ u23,
                         float* __restrict__ out)
{
    int d = threadIdx.x;
    out[d] = fmaxf(unmap_f(u1[d]), unmap_f(u23[d]));
}

extern "C" void kernel_launch(void* const* d_in, const int* in_sizes, int n_in,
                              void* d_out, int out_size, void* d_ws, size_t ws_size,
                              hipStream_t stream) {
    const float* m_emb  = (const float*)d_in[0];
    const float* ddi    = (const float*)d_in[1];
    const float* unrel  = (const float*)d_in[2];
    const float* hidden = (const float*)d_in[3];
    const float* W_ih   = (const float*)d_in[4];
    const float* W_hh   = (const float*)d_in[5];
    const float* b_ih   = (const float*)d_in[6];
    const float* b_hh   = (const float*)d_in[7];
    const float* Wq     = (const float*)d_in[8];
    const float* bq     = (const float*)d_in[9];
    const float* Wk     = (const float*)d_in[10];
    const float* bk     = (const float*)d_in[11];
    const float* Wv     = (const float*)d_in[12];
    const float* bv     = (const float*)d_in[13];
    const int*   divided= (const int*)d_in[14];

    char* ws = (char*)d_ws;
    bf16_t* B1p   = (bf16_t*)(ws + OFF_B1);
    bf16_t* B2p   = (bf16_t*)(ws + OFF_B2);
    bf16_t* B3p   = (bf16_t*)(ws + OFF_B3);
    bf16_t* BVp   = (bf16_t*)(ws + OFF_BV);
    float*  biases= (float*)(ws + OFF_BIAS);
    unsigned* u1  = (unsigned*)(ws + OFF_U1);
    unsigned* u23 = (unsigned*)(ws + OFF_U23);
    int*    counts= (int*)(ws + OFF_CNT);
    int*    idxS  = (int*)(ws + OFF_IDXS);
    int*    idxM1 = (int*)(ws + OFF_IDXM);
    bf16_t* gxc   = (bf16_t*)(ws + OFF_GXC);
    bf16_t* ghc   = (bf16_t*)(ws + OFF_GHC);
    bf16_t* G3c   = (bf16_t*)(ws + OFF_G3C);
    bf16_t* Vt    = (bf16_t*)(ws + OFF_VT);
    bf16_t* Kp    = (bf16_t*)(ws + OFF_KP);
    bf16_t* Vp    = (bf16_t*)(ws + OFF_VP);
    float*  pml   = (float*)(ws + OFF_PML);
    bf16_t* pO    = (bf16_t*)(ws + OFF_PO);

    int ksplit;
    if (ws_size >= OFF_PO + (size_t)8 * 4194304)      ksplit = 8;
    else if (ws_size >= OFF_PO + (size_t)4 * 4194304) ksplit = 4;
    else                                              ksplit = 2;

    float* out   = (float*)d_out;
    float* h_new = out + 256;

    tl_prep_scan<<<dim3(129), dim3(1024), 0, stream>>>(W_ih, W_hh, Wq, Wk, Wv, b_ih, b_hh, bq, bk, bv,
                                                       divided, B1p, B2p, B3p, BVp, biases, u1, u23,
                                                       idxS, idxM1, counts);
    tl_gemm_quad<<<dim3(128, 8), dim3(256), 0, stream>>>(m_emb, hidden, ddi, unrel, divided,
                                                         B1p, B2p, B3p, BVp, biases,
                                                         gxc, ghc, G3c, Vt, idxM1, idxS, counts);
    tl_gru_pack<<<dim3(3072), dim3(256), 0, stream>>>(gxc, ghc, hidden, idxM1, counts, h_new, u1,
                                                      G3c, Vt, Kp, Vp);
    tl_attn<<<dim3(ksplit, 128), dim3(256), 0, stream>>>(G3c, Kp, Vp, counts, ksplit, pml, pO);
    if (ksplit == 8)      tl_merge_t<8><<<dim3(1024), dim3(256), 0, stream>>>(pO, pml, idxS, counts, h_new, u23);
    else if (ksplit == 4) tl_merge_t<4><<<dim3(1024), dim3(256), 0, stream>>>(pO, pml, idxS, counts, h_new, u23);
    else                  tl_merge_t<2><<<dim3(1024), dim3(256), 0, stream>>>(pO, pml, idxS, counts, h_new, u23);
    tl_final<<<dim3(1), dim3(256), 0, stream>>>(u1, u23, out);
}

// Round 15
// 152.592 us; speedup vs baseline: 1.0915x; 1.0915x over previous
//
#include <hip/hip_runtime.h>

typedef __bf16 bf16_t;
typedef __bf16 bf16x8 __attribute__((ext_vector_type(8)));
typedef float f32x4 __attribute__((ext_vector_type(4)));

#define MFMA16(A, B, C) __builtin_amdgcn_mfma_f32_16x16x32_bf16(A, B, C, 0, 0, 0)

static constexpr int N_CODE = 8192;

// ---- workspace layout (bytes), de-aliased ----
static constexpr size_t OFF_B1   = 0;                       // 393216
static constexpr size_t OFF_B2   = OFF_B1 + 393216;         // 393216
static constexpr size_t OFF_B3   = OFF_B2 + 393216;         // 131072
static constexpr size_t OFF_BV   = OFF_B3 + 131072;         // 131072
static constexpr size_t OFF_BIAS = OFF_BV + 131072;         // 8192
static constexpr size_t OFF_U1   = OFF_BIAS + 8192;         // 1024
static constexpr size_t OFF_U23  = OFF_U1 + 1024;           // 1024
static constexpr size_t OFF_CNT  = OFF_U23 + 1024;          // 256
static constexpr size_t OFF_IDXS = OFF_CNT + 256;           // 32768
static constexpr size_t OFF_IDXM = OFF_IDXS + 32768;        // 32768
static constexpr size_t OFF_GXC  = OFF_IDXM + 32768;        // 12582912
static constexpr size_t OFF_GHC  = OFF_GXC + 12582912;      // 12582912
static constexpr size_t OFF_G3C  = OFF_GHC + 12582912;      // 4194304
static constexpr size_t OFF_VT   = OFF_G3C + 4194304;       // 4194304
static constexpr size_t OFF_KP   = OFF_VT + 4194304;        // 2097152
static constexpr size_t OFF_VP   = OFF_KP + 2097152;        // 4194304
static constexpr size_t OFF_PML  = OFF_VP + 4194304;        // 1048576 (ksplit<=16 m,l pairs)
static constexpr size_t OFF_PO   = OFF_PML + 1048576;       // ksplit*4194304
// ksplit=12 needs 92,350,720 B — GUARANTEED (round-7 tier-16 selection proved ws>=93,399,296).
// ksplit=16 needs 109,127,936 B — opportunistic.
// NOTE (round 9): NO device-scope fences / cross-block done-counters (+60us XCD L2 writeback).
// NOTE (round 11): NO register-staged K/V tiles in attn (spills -> 120MB scratch writes).
// NOTE (round 14): NO LDS staging of K/V in attn (105KB LDS -> 1 block/CU, 70.6->91us).
//                  Attn body below is the thrice-proven R5/R13 form — DO NOT restructure.

__device__ __forceinline__ unsigned umap_f(float f) {
    unsigned u = __float_as_uint(f);
    return (u & 0x80000000u) ? ~u : (u | 0x80000000u);   // monotone: larger float -> larger uint
}
__device__ __forceinline__ float unmap_f(unsigned u) {
    unsigned b = (u & 0x80000000u) ? (u & 0x7fffffffu) : ~u;
    return __uint_as_float(b);
}

// ---- fused: block 0 = compaction scan (shfl-based); blocks 1..128 = weight pack ----
__global__ __launch_bounds__(1024)
void tl_prep_scan(const float* __restrict__ W_ih, const float* __restrict__ W_hh,
                  const float* __restrict__ Wq, const float* __restrict__ Wk,
                  const float* __restrict__ Wv,
                  const float* __restrict__ b_ih, const float* __restrict__ b_hh,
                  const float* __restrict__ bq, const float* __restrict__ bk,
                  const float* __restrict__ bv,
                  const int* __restrict__ divided,
                  bf16_t* __restrict__ B1p, bf16_t* __restrict__ B2p,
                  bf16_t* __restrict__ B3p, bf16_t* __restrict__ BVp,
                  float* __restrict__ biases,
                  unsigned* __restrict__ u1, unsigned* __restrict__ u23,
                  int* __restrict__ idxS, int* __restrict__ idxM1, int* __restrict__ counts)
{
    int t = threadIdx.x;
    if (blockIdx.x == 0) {
        __shared__ int w1[16], w23[16];
        int lane = t & 63, wv = t >> 6;
        int d[8]; int c1 = 0, c23 = 0;
#pragma unroll
        for (int i = 0; i < 8; ++i) {
            d[i] = divided[t*8 + i];
            c1  += (d[i] == 0);
            c23 += (d[i] != 0);
        }
        int s1v = c1, s23v = c23;
#pragma unroll
        for (int off = 1; off < 64; off <<= 1) {
            int a1  = __shfl_up(s1v,  off, 64);
            int a23 = __shfl_up(s23v, off, 64);
            if (lane >= off) { s1v += a1; s23v += a23; }
        }
        if (lane == 63) { w1[wv] = s1v; w23[wv] = s23v; }
        __syncthreads();
        if (wv == 0 && lane < 16) {
            int v1 = w1[lane], v23 = w23[lane];
#pragma unroll
            for (int off = 1; off < 16; off <<= 1) {
                int a1  = __shfl_up(v1,  off, 16);
                int a23 = __shfl_up(v23, off, 16);
                if (lane >= off) { v1 += a1; v23 += a23; }
            }
            w1[lane] = v1; w23[lane] = v23;
        }
        __syncthreads();
        int base1  = (wv > 0) ? w1[wv-1]  : 0;
        int base23 = (wv > 0) ? w23[wv-1] : 0;
        int o1  = base1  + s1v  - c1;
        int o23 = base23 + s23v - c23;
#pragma unroll
        for (int i = 0; i < 8; ++i) {
            if (d[i] == 0) idxM1[o1++] = t*8 + i;
            else           idxS[o23++] = t*8 + i;
        }
        if (t == 1023) { counts[0] = w23[15]; counts[1] = w1[15]; }
        return;
    }
    int idx = (blockIdx.x - 1) * 1024 + t;
    const int T1 = 196608, T2 = 196608, T3 = 65536, T4 = 65536;
    for (int i = idx; i < T1 + T2 + T3 + T4; i += 128 * 1024) {
        int which, l;
        if (i < T1)                { which = 0; l = i; }
        else if (i < T1 + T2)      { which = 1; l = i - T1; }
        else if (i < T1 + T2 + T3) { which = 2; l = i - T1 - T2; }
        else                       { which = 3; l = i - T1 - T2 - T3; }
        int j = l & 7, lane = (l >> 3) & 63, kk = (l >> 9) & 7, n16 = l >> 12;
        int k = kk*32 + (lane >> 4)*8 + j;      // K index 0..255
        int n = n16*16 + (lane & 15);           // output column
        if (which == 0)      B1p[l] = (bf16_t)W_ih[n*256 + k];
        else if (which == 1) B2p[l] = (bf16_t)W_hh[n*256 + k];
        else if (which == 2) B3p[l] = (bf16_t)((n < 128) ? Wq[k*128 + n] : Wk[k*128 + (n - 128)]);
        else                 BVp[l] = (bf16_t)Wv[k*256 + n];
    }
    if (idx < 768)       biases[idx] = b_ih[idx];
    else if (idx < 1536) biases[idx] = b_hh[idx - 768];
    else if (idx < 1792) { int q = idx - 1536; biases[idx] = (q < 128) ? bq[q] : bk[q - 128]; }
    else if (idx < 2048) biases[idx] = bv[idx - 1792];
    if (idx < 256) { u1[idx] = 0x007FFFFFu; u23[idx] = 0x007FFFFFu; }  // umap(-inf)
}

__device__ __forceinline__ bf16x8 load_cvt8(const float* p) {
    f32x4 a = *(const f32x4*)p;
    f32x4 b = *(const f32x4*)(p + 4);
    bf16x8 r;
#pragma unroll
    for (int j = 0; j < 4; ++j) { r[j] = (bf16_t)a[j]; r[j+4] = (bf16_t)b[j]; }
    return r;
}

// ---- quad gathered GEMM, WIDE: each wave owns 64 cols (4 n-frags) ----
__global__ __launch_bounds__(256, 2)
void tl_gemm_quad(const float* __restrict__ m_emb, const float* __restrict__ hidden,
                  const float* __restrict__ ddi, const float* __restrict__ unrel,
                  const int* __restrict__ divided,
                  const bf16_t* __restrict__ B1p, const bf16_t* __restrict__ B2p,
                  const bf16_t* __restrict__ B3p, const bf16_t* __restrict__ BVp,
                  const float* __restrict__ biases,
                  bf16_t* __restrict__ gxc, bf16_t* __restrict__ ghc,
                  bf16_t* __restrict__ G3c, bf16_t* __restrict__ Vt,
                  const int* __restrict__ idxM1, const int* __restrict__ idxS,
                  const int* __restrict__ counts)
{
    int y = blockIdx.y;
    const float* A0; const float* A1 = nullptr; int mode = 0;
    const bf16_t* Bp; const float* bias; bf16_t* C; int NOUT; int y0;
    const int* gidx; int cnt;
    if (y < 3)       { A0 = m_emb;  gidx = idxM1; cnt = counts[1]; Bp = B1p; bias = biases;        C = gxc; NOUT = 768; y0 = y; }
    else if (y < 6)  { A0 = hidden; gidx = idxM1; cnt = counts[1]; Bp = B2p; bias = biases + 768;  C = ghc; NOUT = 768; y0 = y - 3; }
    else if (y == 6) { A0 = ddi; A1 = unrel; mode = 2;
                       gidx = idxS;  cnt = counts[0]; Bp = B3p; bias = biases + 1536; C = G3c; NOUT = 256; y0 = 0; }
    else             { A0 = m_emb;  gidx = idxS;  cnt = counts[0]; Bp = BVp; bias = biases + 1792; C = Vt;  NOUT = 256; y0 = 0; }

    int m0 = blockIdx.x * 64;
    if (m0 >= cnt) return;
    int lane = threadIdx.x & 63;
    int w    = threadIdx.x >> 6;
    int rlo = lane & 15, khi = lane >> 4;
    int nbase = y0 * 256 + w * 64;

    const float* arow[4];
#pragma unroll
    for (int m = 0; m < 4; ++m) {
        int row = m0 + m*16 + rlo;
        int src = gidx[(row < cnt) ? row : 0];
        const float* base = A0;
        if (mode == 2) base = (divided[src] == 1) ? A0 : A1;
        arow[m] = base + (size_t)src * 256;
    }
    f32x4 acc[4][4] = {};
    const bf16_t* bptr = Bp + (size_t)(nbase >> 4) * 4096 + lane * 8;
#pragma unroll
    for (int kk = 0; kk < 8; ++kk) {
        bf16x8 bfrag[4];
#pragma unroll
        for (int nf = 0; nf < 4; ++nf)
            bfrag[nf] = *(const bf16x8*)(bptr + nf * 4096 + kk * 512);
#pragma unroll
        for (int m = 0; m < 4; ++m) {
            bf16x8 afrag = load_cvt8(arow[m] + kk*32 + khi*8);
#pragma unroll
            for (int nf = 0; nf < 4; ++nf)
                acc[m][nf] = MFMA16(afrag, bfrag[nf], acc[m][nf]);
        }
    }
#pragma unroll
    for (int nf = 0; nf < 4; ++nf) {
        int col = nbase + nf*16 + rlo;
        float b = bias[col];
#pragma unroll
        for (int m = 0; m < 4; ++m)
#pragma unroll
            for (int r = 0; r < 4; ++r) {
                int row = m0 + m*16 + khi*4 + r;
                C[(size_t)row * NOUT + col] = (bf16_t)(acc[m][nf][r] + b);
            }
    }
}

// ---- fused gru (blocks 0..1023) + pack (blocks 1024..3071) ----
__global__ __launch_bounds__(256)
void tl_gru_pack(const bf16_t* __restrict__ gx, const bf16_t* __restrict__ gh,
                 const float* __restrict__ hidden,
                 const int* __restrict__ idxM1, const int* __restrict__ counts,
                 float* __restrict__ h_new, unsigned* __restrict__ u1,
                 const bf16_t* __restrict__ G3c, const bf16_t* __restrict__ Vt,
                 bf16_t* __restrict__ Kp, bf16_t* __restrict__ Vp)
{
    if (blockIdx.x < 1024) {
        int nM1 = counts[1];
        int i0 = blockIdx.x * 8;
        if (i0 >= nM1) return;
        int j = threadIdx.x;
        int iend = (i0 + 8 < nM1) ? i0 + 8 : nM1;
        float cmax = -1e30f;
        for (int i = i0; i < iend; ++i) {
            int row = idxM1[i];
            float xr = (float)gx[(size_t)i*768 + j];
            float xz = (float)gx[(size_t)i*768 + 256 + j];
            float xn = (float)gx[(size_t)i*768 + 512 + j];
            float hr = (float)gh[(size_t)i*768 + j];
            float hz = (float)gh[(size_t)i*768 + 256 + j];
            float hn = (float)gh[(size_t)i*768 + 512 + j];
            float h  = hidden[(size_t)row*256 + j];
            float r = 1.f/(1.f + __expf(-(xr + hr)));
            float z = 1.f/(1.f + __expf(-(xz + hz)));
            float n = tanhf(xn + r*hn);
            float hg = (1.f - z)*n + z*h;
            h_new[(size_t)row*256 + j] = hg;
            cmax = fmaxf(cmax, hg);
        }
        atomicMax(&u1[j], umap_f(cmax));
        return;
    }
    int nS = counts[0];
    int nT = (nS + 63) >> 6;
    int r = (blockIdx.x - 1024) * 4 + (threadIdx.x >> 6);
    if (r >= nT * 64) return;
    int t = threadIdx.x & 63;
    bool valid = r < nS;
    if (t < 16) {                 // K b-frags: [kt][ks4][nf4][lane][8]
        bf16x8 v = {};
        if (valid) v = *(const bf16x8*)(G3c + (size_t)r*256 + 128 + t*8);
        int kt = r >> 6, keyin = r & 63;
        int ks = t >> 2, lhi = t & 3, nf = keyin >> 4;
        int lane = (lhi << 4) | (keyin & 15);
        *(bf16x8*)(Kp + ((((size_t)kt*4 + ks)*4 + nf)*64 + lane)*8) = v;
    } else if (t < 48) {          // V b-frags: [kt][ks2][nf16][lane][8]
        int j8 = t - 16;
        int d0 = j8 * 8;
        bf16x8 v = {};
        if (valid) v = *(const bf16x8*)(Vt + (size_t)r*256 + d0);
        int kt = r >> 6, ks2 = (r >> 5) & 1, jj = r & 7, lhi = (r >> 3) & 3;
#pragma unroll
        for (int q = 0; q < 8; ++q) {
            int d = d0 + q;
            int nf = d >> 4;
            int lane = (lhi << 4) | (d & 15);
            Vp[((((size_t)kt*2 + ks2)*16 + nf)*64 + lane)*8 + jj] = v[q];
        }
    }
}

// ---- flash attention (BYTE-STABLE R5/R13 body); grid (ksplit, 128) XCD-locality swap ----
__global__ __launch_bounds__(256, 2)
void tl_attn(const bf16_t* __restrict__ G3c, const bf16_t* __restrict__ Kp,
             const bf16_t* __restrict__ Vp, const int* __restrict__ counts,
             int ksplit, float* __restrict__ pml, bf16_t* __restrict__ pO)
{
    int nS = counts[0];
    int nT = (nS + 63) >> 6;
    int qt = blockIdx.y;
    if (qt >= nT) return;
    int c = blockIdx.x;
    int kt0 = (nT * c) / ksplit, kt1 = (nT * (c + 1)) / ksplit;

    int lane = threadIdx.x & 63;
    int w    = threadIdx.x >> 6;
    int rlo = lane & 15, khi = lane >> 4;
    int qbase = qt * 64 + w * 16;

    __shared__ __align__(16) bf16_t P_lds[4][16][72];   // per-wave private strip

    bf16x8 aQ[4];
    const bf16_t* qrow = G3c + (size_t)(qbase + rlo) * 256 + khi * 8;
#pragma unroll
    for (int ks = 0; ks < 4; ++ks) aQ[ks] = *(const bf16x8*)(qrow + ks * 32);

    float m_run[4], l_run[4];
#pragma unroll
    for (int r = 0; r < 4; ++r) { m_run[r] = -1e30f; l_run[r] = 0.f; }
    f32x4 O[16];
#pragma unroll
    for (int i = 0; i < 16; ++i) O[i] = (f32x4){0.f, 0.f, 0.f, 0.f};

    const float scale = 0.088388347648318447f;   // 1/sqrt(128)

    for (int kt = kt0; kt < kt1; ++kt) {
        f32x4 s[4] = {};
#pragma unroll
        for (int ks = 0; ks < 4; ++ks) {
            const bf16_t* kp = Kp + ((size_t)(kt*4 + ks) * 256 + lane) * 8;
#pragma unroll
            for (int nf = 0; nf < 4; ++nf) {
                bf16x8 bK = *(const bf16x8*)(kp + nf * 512);
                s[nf] = MFMA16(aQ[ks], bK, s[nf]);
            }
        }
        int kbase = kt * 64;
#pragma unroll
        for (int nf = 0; nf < 4; ++nf) {
            bool valid = (kbase + nf*16 + rlo) < nS;
#pragma unroll
            for (int r = 0; r < 4; ++r) {
                float v = s[nf][r] * scale;
                s[nf][r] = valid ? v : -1e30f;
            }
        }
        float pm[4];
#pragma unroll
        for (int r = 0; r < 4; ++r)
            pm[r] = fmaxf(fmaxf(s[0][r], s[1][r]), fmaxf(s[2][r], s[3][r]));
#pragma unroll
        for (int off = 1; off < 16; off <<= 1)
#pragma unroll
            for (int r = 0; r < 4; ++r) pm[r] = fmaxf(pm[r], __shfl_xor(pm[r], off, 64));

        float mn[4], sc[4], rs[4];
#pragma unroll
        for (int r = 0; r < 4; ++r) {
            mn[r] = fmaxf(m_run[r], pm[r]);
            sc[r] = __expf(m_run[r] - mn[r]);
            m_run[r] = mn[r];
            rs[r] = 0.f;
        }
#pragma unroll
        for (int nf = 0; nf < 4; ++nf)
#pragma unroll
            for (int r = 0; r < 4; ++r) {
                float p = __expf(s[nf][r] - mn[r]);
                s[nf][r] = p;
                rs[r] += p;
            }
#pragma unroll
        for (int off = 1; off < 16; off <<= 1)
#pragma unroll
            for (int r = 0; r < 4; ++r) rs[r] += __shfl_xor(rs[r], off, 64);
#pragma unroll
        for (int r = 0; r < 4; ++r) l_run[r] = l_run[r]*sc[r] + rs[r];
#pragma unroll
        for (int nf = 0; nf < 16; ++nf)
#pragma unroll
            for (int r = 0; r < 4; ++r) O[nf][r] *= sc[r];
        // P -> per-wave LDS strip, read back in a-frag layout (in-wave dep, no barrier needed)
#pragma unroll
        for (int nf = 0; nf < 4; ++nf)
#pragma unroll
            for (int r = 0; r < 4; ++r)
                P_lds[w][khi*4 + r][nf*16 + rlo] = (bf16_t)s[nf][r];
#pragma unroll
        for (int ks2 = 0; ks2 < 2; ++ks2) {
            bf16x8 pa = *(const bf16x8*)&P_lds[w][rlo][ks2*32 + khi*8];
            const bf16_t* vp = Vp + ((size_t)(kt*2 + ks2) * 1024 + lane) * 8;
#pragma unroll
            for (int nf = 0; nf < 16; ++nf) {
                bf16x8 bV = *(const bf16x8*)(vp + nf * 512);
                O[nf] = MFMA16(pa, bV, O[nf]);
            }
        }
    }
    if (rlo == 0) {
#pragma unroll
        for (int r = 0; r < 4; ++r) {
            int qc = qbase + khi*4 + r;
            pml[((size_t)c*N_CODE + qc)*2 + 0] = m_run[r];
            pml[((size_t)c*N_CODE + qc)*2 + 1] = l_run[r];
        }
    }
#pragma unroll
    for (int nf = 0; nf < 16; ++nf) {
        int d = nf*16 + rlo;
#pragma unroll
        for (int r = 0; r < 4; ++r) {
            int qc = qbase + khi*4 + r;
            pO[((size_t)c*N_CODE + qc)*256 + d] = (bf16_t)O[nf][r];
        }
    }
}

// ---- merge key-split partials, VECTORIZED ----
template<int KS>
__global__ __launch_bounds__(256)
void tl_merge_t(const bf16_t* __restrict__ pO, const float* __restrict__ pml,
                const int* __restrict__ idxS, const int* __restrict__ counts,
                float* __restrict__ h_new, unsigned* __restrict__ u23)
{
    int nS = counts[0];
    int i0 = blockIdx.x * 8;
    if (i0 >= nS) return;
    int tid = threadIdx.x;
    int qi = tid >> 5;
    int j8 = tid & 31;
    int q  = i0 + qi;

    __shared__ unsigned smax[256];
    smax[tid] = 0x007FFFFFu;      // umap(-inf)
    __syncthreads();

    if (q < nS) {
        float m = -1e30f;
#pragma unroll
        for (int cc = 0; cc < KS; ++cc)
            m = fmaxf(m, pml[((size_t)cc*N_CODE + q)*2 + 0]);
        float e[KS]; float l = 0.f;
#pragma unroll
        for (int cc = 0; cc < KS; ++cc) {
            e[cc] = __expf(pml[((size_t)cc*N_CODE + q)*2 + 0] - m);
            l += pml[((size_t)cc*N_CODE + q)*2 + 1] * e[cc];
        }
        float acc[8] = {};
#pragma unroll
        for (int cc = 0; cc < KS; ++cc) {
            bf16x8 v = *(const bf16x8*)(pO + ((size_t)cc*N_CODE + q)*256 + j8*8);
#pragma unroll
            for (int k = 0; k < 8; ++k) acc[k] += (float)v[k] * e[cc];
        }
        float linv = 1.f / fmaxf(l, 1e-30f);
        f32x4 o0, o1;
#pragma unroll
        for (int k = 0; k < 8; ++k) {
            float val = tanhf(acc[k] * linv);
            if (k < 4) o0[k] = val; else o1[k-4] = val;
            atomicMax(&smax[j8*8 + k], umap_f(val));   // LDS atomic (block-local)
        }
        float* dst = h_new + (size_t)idxS[q]*256 + j8*8;
        *(f32x4*)dst = o0;
        *(f32x4*)(dst + 4) = o1;
    }
    __syncthreads();
    atomicMax(&u23[tid], smax[tid]);   // one global atomic per column per block
}

__global__ void tl_final(const unsigned* __restrict__ u1, const unsigned* __restrict__ u23,
                         float* __restrict__ out)
{
    int d = threadIdx.x;
    out[d] = fmaxf(unmap_f(u1[d]), unmap_f(u23[d]));
}

extern "C" void kernel_launch(void* const* d_in, const int* in_sizes, int n_in,
                              void* d_out, int out_size, void* d_ws, size_t ws_size,
                              hipStream_t stream) {
    const float* m_emb  = (const float*)d_in[0];
    const float* ddi    = (const float*)d_in[1];
    const float* unrel  = (const float*)d_in[2];
    const float* hidden = (const float*)d_in[3];
    const float* W_ih   = (const float*)d_in[4];
    const float* W_hh   = (const float*)d_in[5];
    const float* b_ih   = (const float*)d_in[6];
    const float* b_hh   = (const float*)d_in[7];
    const float* Wq     = (const float*)d_in[8];
    const float* bq     = (const float*)d_in[9];
    const float* Wk     = (const float*)d_in[10];
    const float* bk     = (const float*)d_in[11];
    const float* Wv     = (const float*)d_in[12];
    const float* bv     = (const float*)d_in[13];
    const int*   divided= (const int*)d_in[14];

    char* ws = (char*)d_ws;
    bf16_t* B1p   = (bf16_t*)(ws + OFF_B1);
    bf16_t* B2p   = (bf16_t*)(ws + OFF_B2);
    bf16_t* B3p   = (bf16_t*)(ws + OFF_B3);
    bf16_t* BVp   = (bf16_t*)(ws + OFF_BV);
    float*  biases= (float*)(ws + OFF_BIAS);
    unsigned* u1  = (unsigned*)(ws + OFF_U1);
    unsigned* u23 = (unsigned*)(ws + OFF_U23);
    int*    counts= (int*)(ws + OFF_CNT);
    int*    idxS  = (int*)(ws + OFF_IDXS);
    int*    idxM1 = (int*)(ws + OFF_IDXM);
    bf16_t* gxc   = (bf16_t*)(ws + OFF_GXC);
    bf16_t* ghc   = (bf16_t*)(ws + OFF_GHC);
    bf16_t* G3c   = (bf16_t*)(ws + OFF_G3C);
    bf16_t* Vt    = (bf16_t*)(ws + OFF_VT);
    bf16_t* Kp    = (bf16_t*)(ws + OFF_KP);
    bf16_t* Vp    = (bf16_t*)(ws + OFF_VP);
    float*  pml   = (float*)(ws + OFF_PML);
    bf16_t* pO    = (bf16_t*)(ws + OFF_PO);

    // key-split tiers: 16 if ws allows, else 12 (guaranteed by round-7 proof), else 8/4/2
    int ksplit;
    if (ws_size >= OFF_PO + (size_t)16 * 4194304)      ksplit = 16;
    else if (ws_size >= OFF_PO + (size_t)12 * 4194304) ksplit = 12;
    else if (ws_size >= OFF_PO + (size_t)8 * 4194304)  ksplit = 8;
    else if (ws_size >= OFF_PO + (size_t)4 * 4194304)  ksplit = 4;
    else                                               ksplit = 2;

    float* out   = (float*)d_out;
    float* h_new = out + 256;

    tl_prep_scan<<<dim3(129), dim3(1024), 0, stream>>>(W_ih, W_hh, Wq, Wk, Wv, b_ih, b_hh, bq, bk, bv,
                                                       divided, B1p, B2p, B3p, BVp, biases, u1, u23,
                                                       idxS, idxM1, counts);
    tl_gemm_quad<<<dim3(128, 8), dim3(256), 0, stream>>>(m_emb, hidden, ddi, unrel, divided,
                                                         B1p, B2p, B3p, BVp, biases,
                                                         gxc, ghc, G3c, Vt, idxM1, idxS, counts);
    tl_gru_pack<<<dim3(3072), dim3(256), 0, stream>>>(gxc, ghc, hidden, idxM1, counts, h_new, u1,
                                                      G3c, Vt, Kp, Vp);
    tl_attn<<<dim3(ksplit, 128), dim3(256), 0, stream>>>(G3c, Kp, Vp, counts, ksplit, pml, pO);
    if (ksplit == 16)      tl_merge_t<16><<<dim3(1024), dim3(256), 0, stream>>>(pO, pml, idxS, counts, h_new, u23);
    else if (ksplit == 12) tl_merge_t<12><<<dim3(1024), dim3(256), 0, stream>>>(pO, pml, idxS, counts, h_new, u23);
    else if (ksplit == 8)  tl_merge_t<8><<<dim3(1024), dim3(256), 0, stream>>>(pO, pml, idxS, counts, h_new, u23);
    else if (ksplit == 4)  tl_merge_t<4><<<dim3(1024), dim3(256), 0, stream>>>(pO, pml, idxS, counts, h_new, u23);
    else                   tl_merge_t<2><<<dim3(1024), dim3(256), 0, stream>>>(pO, pml, idxS, counts, h_new, u23);
    tl_final<<<dim3(1), dim3(256), 0, stream>>>(u1, u23, out);
}

// Round 16
// 147.071 us; speedup vs baseline: 1.1325x; 1.0375x over previous
//
#include <hip/hip_runtime.h>

typedef __bf16 bf16_t;
typedef __bf16 bf16x8 __attribute__((ext_vector_type(8)));
typedef float f32x4 __attribute__((ext_vector_type(4)));

#define MFMA16(A, B, C) __builtin_amdgcn_mfma_f32_16x16x32_bf16(A, B, C, 0, 0, 0)

static constexpr int N_CODE = 8192;

// ---- workspace layout (bytes), de-aliased ----
static constexpr size_t OFF_B1   = 0;                       // 393216
static constexpr size_t OFF_B2   = OFF_B1 + 393216;         // 393216
static constexpr size_t OFF_B3   = OFF_B2 + 393216;         // 131072
static constexpr size_t OFF_BV   = OFF_B3 + 131072;         // 131072
static constexpr size_t OFF_BIAS = OFF_BV + 131072;         // 8192
static constexpr size_t OFF_U1   = OFF_BIAS + 8192;         // 1024
static constexpr size_t OFF_U23  = OFF_U1 + 1024;           // 1024
static constexpr size_t OFF_CNT  = OFF_U23 + 1024;          // 256
static constexpr size_t OFF_IDXS = OFF_CNT + 256;           // 32768
static constexpr size_t OFF_IDXM = OFF_IDXS + 32768;        // 32768
static constexpr size_t OFF_GXC  = OFF_IDXM + 32768;        // 12582912
static constexpr size_t OFF_GHC  = OFF_GXC + 12582912;      // 12582912
static constexpr size_t OFF_G3C  = OFF_GHC + 12582912;      // 4194304
static constexpr size_t OFF_VT   = OFF_G3C + 4194304;       // 4194304
static constexpr size_t OFF_KP   = OFF_VT + 4194304;        // 2097152
static constexpr size_t OFF_VP   = OFF_KP + 2097152;        // 4194304
static constexpr size_t OFF_PML  = OFF_VP + 4194304;        // 1048576
static constexpr size_t OFF_PO   = OFF_PML + 1048576;       // ksplit*4194304
// NOTE (round 9): NO device-scope fences / cross-block done-counters (+60us XCD L2 writeback).
// NOTE (round 11): NO register-staged K/V tiles in attn (spills -> 120MB scratch writes).
// NOTE (round 14): NO LDS staging of K/V in attn (105KB LDS -> 1 block/CU, 70.6->91us).
// NOTE (round 15): ksplit=16 is NEUTRAL-NEGATIVE (occupancy capped per-CU; pO epilogue 2x).
//                  ksplit=8 is the measured optimum. Attn body is the R5/R13 proven form.

__device__ __forceinline__ unsigned umap_f(float f) {
    unsigned u = __float_as_uint(f);
    return (u & 0x80000000u) ? ~u : (u | 0x80000000u);   // monotone: larger float -> larger uint
}
__device__ __forceinline__ float unmap_f(unsigned u) {
    unsigned b = (u & 0x80000000u) ? (u & 0x7fffffffu) : ~u;
    return __uint_as_float(b);
}

// ---- fused: block 0 = compaction scan (shfl-based); blocks 1..128 = weight pack ----
__global__ __launch_bounds__(1024)
void tl_prep_scan(const float* __restrict__ W_ih, const float* __restrict__ W_hh,
                  const float* __restrict__ Wq, const float* __restrict__ Wk,
                  const float* __restrict__ Wv,
                  const float* __restrict__ b_ih, const float* __restrict__ b_hh,
                  const float* __restrict__ bq, const float* __restrict__ bk,
                  const float* __restrict__ bv,
                  const int* __restrict__ divided,
                  bf16_t* __restrict__ B1p, bf16_t* __restrict__ B2p,
                  bf16_t* __restrict__ B3p, bf16_t* __restrict__ BVp,
                  float* __restrict__ biases,
                  unsigned* __restrict__ u1, unsigned* __restrict__ u23,
                  int* __restrict__ idxS, int* __restrict__ idxM1, int* __restrict__ counts)
{
    int t = threadIdx.x;
    if (blockIdx.x == 0) {
        __shared__ int w1[16], w23[16];
        int lane = t & 63, wv = t >> 6;
        int d[8]; int c1 = 0, c23 = 0;
#pragma unroll
        for (int i = 0; i < 8; ++i) {
            d[i] = divided[t*8 + i];
            c1  += (d[i] == 0);
            c23 += (d[i] != 0);
        }
        int s1v = c1, s23v = c23;
#pragma unroll
        for (int off = 1; off < 64; off <<= 1) {
            int a1  = __shfl_up(s1v,  off, 64);
            int a23 = __shfl_up(s23v, off, 64);
            if (lane >= off) { s1v += a1; s23v += a23; }
        }
        if (lane == 63) { w1[wv] = s1v; w23[wv] = s23v; }
        __syncthreads();
        if (wv == 0 && lane < 16) {
            int v1 = w1[lane], v23 = w23[lane];
#pragma unroll
            for (int off = 1; off < 16; off <<= 1) {
                int a1  = __shfl_up(v1,  off, 16);
                int a23 = __shfl_up(v23, off, 16);
                if (lane >= off) { v1 += a1; v23 += a23; }
            }
            w1[lane] = v1; w23[lane] = v23;
        }
        __syncthreads();
        int base1  = (wv > 0) ? w1[wv-1]  : 0;
        int base23 = (wv > 0) ? w23[wv-1] : 0;
        int o1  = base1  + s1v  - c1;
        int o23 = base23 + s23v - c23;
#pragma unroll
        for (int i = 0; i < 8; ++i) {
            if (d[i] == 0) idxM1[o1++] = t*8 + i;
            else           idxS[o23++] = t*8 + i;
        }
        if (t == 1023) { counts[0] = w23[15]; counts[1] = w1[15]; }
        return;
    }
    int idx = (blockIdx.x - 1) * 1024 + t;
    const int T1 = 196608, T2 = 196608, T3 = 65536, T4 = 65536;
    for (int i = idx; i < T1 + T2 + T3 + T4; i += 128 * 1024) {
        int which, l;
        if (i < T1)                { which = 0; l = i; }
        else if (i < T1 + T2)      { which = 1; l = i - T1; }
        else if (i < T1 + T2 + T3) { which = 2; l = i - T1 - T2; }
        else                       { which = 3; l = i - T1 - T2 - T3; }
        int j = l & 7, lane = (l >> 3) & 63, kk = (l >> 9) & 7, n16 = l >> 12;
        int k = kk*32 + (lane >> 4)*8 + j;      // K index 0..255
        int n = n16*16 + (lane & 15);           // output column
        if (which == 0)      B1p[l] = (bf16_t)W_ih[n*256 + k];
        else if (which == 1) B2p[l] = (bf16_t)W_hh[n*256 + k];
        else if (which == 2) B3p[l] = (bf16_t)((n < 128) ? Wq[k*128 + n] : Wk[k*128 + (n - 128)]);
        else                 BVp[l] = (bf16_t)Wv[k*256 + n];
    }
    if (idx < 768)       biases[idx] = b_ih[idx];
    else if (idx < 1536) biases[idx] = b_hh[idx - 768];
    else if (idx < 1792) { int q = idx - 1536; biases[idx] = (q < 128) ? bq[q] : bk[q - 128]; }
    else if (idx < 2048) biases[idx] = bv[idx - 1792];
    if (idx < 256) { u1[idx] = 0x007FFFFFu; u23[idx] = 0x007FFFFFu; }  // umap(-inf)
}

__device__ __forceinline__ bf16x8 load_cvt8(const float* p) {
    f32x4 a = *(const f32x4*)p;
    f32x4 b = *(const f32x4*)(p + 4);
    bf16x8 r;
#pragma unroll
    for (int j = 0; j < 4; ++j) { r[j] = (bf16_t)a[j]; r[j+4] = (bf16_t)b[j]; }
    return r;
}

// ---- quad gathered GEMM, WIDE: each wave owns 64 cols (4 n-frags) ----
__global__ __launch_bounds__(256, 2)
void tl_gemm_quad(const float* __restrict__ m_emb, const float* __restrict__ hidden,
                  const float* __restrict__ ddi, const float* __restrict__ unrel,
                  const int* __restrict__ divided,
                  const bf16_t* __restrict__ B1p, const bf16_t* __restrict__ B2p,
                  const bf16_t* __restrict__ B3p, const bf16_t* __restrict__ BVp,
                  const float* __restrict__ biases,
                  bf16_t* __restrict__ gxc, bf16_t* __restrict__ ghc,
                  bf16_t* __restrict__ G3c, bf16_t* __restrict__ Vt,
                  const int* __restrict__ idxM1, const int* __restrict__ idxS,
                  const int* __restrict__ counts)
{
    int y = blockIdx.y;
    const float* A0; const float* A1 = nullptr; int mode = 0;
    const bf16_t* Bp; const float* bias; bf16_t* C; int NOUT; int y0;
    const int* gidx; int cnt;
    if (y < 3)       { A0 = m_emb;  gidx = idxM1; cnt = counts[1]; Bp = B1p; bias = biases;        C = gxc; NOUT = 768; y0 = y; }
    else if (y < 6)  { A0 = hidden; gidx = idxM1; cnt = counts[1]; Bp = B2p; bias = biases + 768;  C = ghc; NOUT = 768; y0 = y - 3; }
    else if (y == 6) { A0 = ddi; A1 = unrel; mode = 2;
                       gidx = idxS;  cnt = counts[0]; Bp = B3p; bias = biases + 1536; C = G3c; NOUT = 256; y0 = 0; }
    else             { A0 = m_emb;  gidx = idxS;  cnt = counts[0]; Bp = BVp; bias = biases + 1792; C = Vt;  NOUT = 256; y0 = 0; }

    int m0 = blockIdx.x * 64;
    if (m0 >= cnt) return;
    int lane = threadIdx.x & 63;
    int w    = threadIdx.x >> 6;
    int rlo = lane & 15, khi = lane >> 4;
    int nbase = y0 * 256 + w * 64;

    const float* arow[4];
#pragma unroll
    for (int m = 0; m < 4; ++m) {
        int row = m0 + m*16 + rlo;
        int src = gidx[(row < cnt) ? row : 0];
        const float* base = A0;
        if (mode == 2) base = (divided[src] == 1) ? A0 : A1;
        arow[m] = base + (size_t)src * 256;
    }
    f32x4 acc[4][4] = {};
    const bf16_t* bptr = Bp + (size_t)(nbase >> 4) * 4096 + lane * 8;
#pragma unroll
    for (int kk = 0; kk < 8; ++kk) {
        bf16x8 bfrag[4];
#pragma unroll
        for (int nf = 0; nf < 4; ++nf)
            bfrag[nf] = *(const bf16x8*)(bptr + nf * 4096 + kk * 512);
#pragma unroll
        for (int m = 0; m < 4; ++m) {
            bf16x8 afrag = load_cvt8(arow[m] + kk*32 + khi*8);
#pragma unroll
            for (int nf = 0; nf < 4; ++nf)
                acc[m][nf] = MFMA16(afrag, bfrag[nf], acc[m][nf]);
        }
    }
#pragma unroll
    for (int nf = 0; nf < 4; ++nf) {
        int col = nbase + nf*16 + rlo;
        float b = bias[col];
#pragma unroll
        for (int m = 0; m < 4; ++m)
#pragma unroll
            for (int r = 0; r < 4; ++r) {
                int row = m0 + m*16 + khi*4 + r;
                C[(size_t)row * NOUT + col] = (bf16_t)(acc[m][nf][r] + b);
            }
    }
}

// ---- fused gru (blocks 0..1023) + pack (blocks 1024..3071) ----
__global__ __launch_bounds__(256)
void tl_gru_pack(const bf16_t* __restrict__ gx, const bf16_t* __restrict__ gh,
                 const float* __restrict__ hidden,
                 const int* __restrict__ idxM1, const int* __restrict__ counts,
                 float* __restrict__ h_new, unsigned* __restrict__ u1,
                 const bf16_t* __restrict__ G3c, const bf16_t* __restrict__ Vt,
                 bf16_t* __restrict__ Kp, bf16_t* __restrict__ Vp)
{
    if (blockIdx.x < 1024) {
        int nM1 = counts[1];
        int i0 = blockIdx.x * 8;
        if (i0 >= nM1) return;
        int j = threadIdx.x;
        int iend = (i0 + 8 < nM1) ? i0 + 8 : nM1;
        float cmax = -1e30f;
        for (int i = i0; i < iend; ++i) {
            int row = idxM1[i];
            float xr = (float)gx[(size_t)i*768 + j];
            float xz = (float)gx[(size_t)i*768 + 256 + j];
            float xn = (float)gx[(size_t)i*768 + 512 + j];
            float hr = (float)gh[(size_t)i*768 + j];
            float hz = (float)gh[(size_t)i*768 + 256 + j];
            float hn = (float)gh[(size_t)i*768 + 512 + j];
            float h  = hidden[(size_t)row*256 + j];
            float r = 1.f/(1.f + __expf(-(xr + hr)));
            float z = 1.f/(1.f + __expf(-(xz + hz)));
            float n = tanhf(xn + r*hn);
            float hg = (1.f - z)*n + z*h;
            h_new[(size_t)row*256 + j] = hg;
            cmax = fmaxf(cmax, hg);
        }
        atomicMax(&u1[j], umap_f(cmax));
        return;
    }
    int nS = counts[0];
    int nT = (nS + 63) >> 6;
    int r = (blockIdx.x - 1024) * 4 + (threadIdx.x >> 6);
    if (r >= nT * 64) return;
    int t = threadIdx.x & 63;
    bool valid = r < nS;
    if (t < 16) {                 // K b-frags: [kt][ks4][nf4][lane][8]
        bf16x8 v = {};
        if (valid) v = *(const bf16x8*)(G3c + (size_t)r*256 + 128 + t*8);
        int kt = r >> 6, keyin = r & 63;
        int ks = t >> 2, lhi = t & 3, nf = keyin >> 4;
        int lane = (lhi << 4) | (keyin & 15);
        *(bf16x8*)(Kp + ((((size_t)kt*4 + ks)*4 + nf)*64 + lane)*8) = v;
    } else if (t < 48) {          // V b-frags: [kt][ks2][nf16][lane][8]
        int j8 = t - 16;
        int d0 = j8 * 8;
        bf16x8 v = {};
        if (valid) v = *(const bf16x8*)(Vt + (size_t)r*256 + d0);
        int kt = r >> 6, ks2 = (r >> 5) & 1, jj = r & 7, lhi = (r >> 3) & 3;
#pragma unroll
        for (int q = 0; q < 8; ++q) {
            int d = d0 + q;
            int nf = d >> 4;
            int lane = (lhi << 4) | (d & 15);
            Vp[((((size_t)kt*2 + ks2)*16 + nf)*64 + lane)*8 + jj] = v[q];
        }
    }
}

// ---- flash attention (BYTE-STABLE R5/R13 body); grid (ksplit, 128) XCD-locality swap ----
__global__ __launch_bounds__(256, 2)
void tl_attn(const bf16_t* __restrict__ G3c, const bf16_t* __restrict__ Kp,
             const bf16_t* __restrict__ Vp, const int* __restrict__ counts,
             int ksplit, float* __restrict__ pml, bf16_t* __restrict__ pO)
{
    int nS = counts[0];
    int nT = (nS + 63) >> 6;
    int qt = blockIdx.y;
    if (qt >= nT) return;
    int c = blockIdx.x;
    int kt0 = (nT * c) / ksplit, kt1 = (nT * (c + 1)) / ksplit;

    int lane = threadIdx.x & 63;
    int w    = threadIdx.x >> 6;
    int rlo = lane & 15, khi = lane >> 4;
    int qbase = qt * 64 + w * 16;

    __shared__ __align__(16) bf16_t P_lds[4][16][72];   // per-wave private strip

    bf16x8 aQ[4];
    const bf16_t* qrow = G3c + (size_t)(qbase + rlo) * 256 + khi * 8;
#pragma unroll
    for (int ks = 0; ks < 4; ++ks) aQ[ks] = *(const bf16x8*)(qrow + ks * 32);

    float m_run[4], l_run[4];
#pragma unroll
    for (int r = 0; r < 4; ++r) { m_run[r] = -1e30f; l_run[r] = 0.f; }
    f32x4 O[16];
#pragma unroll
    for (int i = 0; i < 16; ++i) O[i] = (f32x4){0.f, 0.f, 0.f, 0.f};

    const float scale = 0.088388347648318447f;   // 1/sqrt(128)

    for (int kt = kt0; kt < kt1; ++kt) {
        f32x4 s[4] = {};
#pragma unroll
        for (int ks = 0; ks < 4; ++ks) {
            const bf16_t* kp = Kp + ((size_t)(kt*4 + ks) * 256 + lane) * 8;
#pragma unroll
            for (int nf = 0; nf < 4; ++nf) {
                bf16x8 bK = *(const bf16x8*)(kp + nf * 512);
                s[nf] = MFMA16(aQ[ks], bK, s[nf]);
            }
        }
        int kbase = kt * 64;
#pragma unroll
        for (int nf = 0; nf < 4; ++nf) {
            bool valid = (kbase + nf*16 + rlo) < nS;
#pragma unroll
            for (int r = 0; r < 4; ++r) {
                float v = s[nf][r] * scale;
                s[nf][r] = valid ? v : -1e30f;
            }
        }
        float pm[4];
#pragma unroll
        for (int r = 0; r < 4; ++r)
            pm[r] = fmaxf(fmaxf(s[0][r], s[1][r]), fmaxf(s[2][r], s[3][r]));
#pragma unroll
        for (int off = 1; off < 16; off <<= 1)
#pragma unroll
            for (int r = 0; r < 4; ++r) pm[r] = fmaxf(pm[r], __shfl_xor(pm[r], off, 64));

        float mn[4], sc[4], rs[4];
#pragma unroll
        for (int r = 0; r < 4; ++r) {
            mn[r] = fmaxf(m_run[r], pm[r]);
            sc[r] = __expf(m_run[r] - mn[r]);
            m_run[r] = mn[r];
            rs[r] = 0.f;
        }
#pragma unroll
        for (int nf = 0; nf < 4; ++nf)
#pragma unroll
            for (int r = 0; r < 4; ++r) {
                float p = __expf(s[nf][r] - mn[r]);
                s[nf][r] = p;
                rs[r] += p;
            }
#pragma unroll
        for (int off = 1; off < 16; off <<= 1)
#pragma unroll
            for (int r = 0; r < 4; ++r) rs[r] += __shfl_xor(rs[r], off, 64);
#pragma unroll
        for (int r = 0; r < 4; ++r) l_run[r] = l_run[r]*sc[r] + rs[r];
#pragma unroll
        for (int nf = 0; nf < 16; ++nf)
#pragma unroll
            for (int r = 0; r < 4; ++r) O[nf][r] *= sc[r];
        // P -> per-wave LDS strip, read back in a-frag layout (in-wave dep, no barrier needed)
#pragma unroll
        for (int nf = 0; nf < 4; ++nf)
#pragma unroll
            for (int r = 0; r < 4; ++r)
                P_lds[w][khi*4 + r][nf*16 + rlo] = (bf16_t)s[nf][r];
#pragma unroll
        for (int ks2 = 0; ks2 < 2; ++ks2) {
            bf16x8 pa = *(const bf16x8*)&P_lds[w][rlo][ks2*32 + khi*8];
            const bf16_t* vp = Vp + ((size_t)(kt*2 + ks2) * 1024 + lane) * 8;
#pragma unroll
            for (int nf = 0; nf < 16; ++nf) {
                bf16x8 bV = *(const bf16x8*)(vp + nf * 512);
                O[nf] = MFMA16(pa, bV, O[nf]);
            }
        }
    }
    if (rlo == 0) {
#pragma unroll
        for (int r = 0; r < 4; ++r) {
            int qc = qbase + khi*4 + r;
            pml[((size_t)c*N_CODE + qc)*2 + 0] = m_run[r];
            pml[((size_t)c*N_CODE + qc)*2 + 1] = l_run[r];
        }
    }
#pragma unroll
    for (int nf = 0; nf < 16; ++nf) {
        int d = nf*16 + rlo;
#pragma unroll
        for (int r = 0; r < 4; ++r) {
            int qc = qbase + khi*4 + r;
            pO[((size_t)c*N_CODE + qc)*256 + d] = (bf16_t)O[nf][r];
        }
    }
}

// ---- merge key-split partials, VECTORIZED ----
template<int KS>
__global__ __launch_bounds__(256)
void tl_merge_t(const bf16_t* __restrict__ pO, const float* __restrict__ pml,
                const int* __restrict__ idxS, const int* __restrict__ counts,
                float* __restrict__ h_new, unsigned* __restrict__ u23)
{
    int nS = counts[0];
    int i0 = blockIdx.x * 8;
    if (i0 >= nS) return;
    int tid = threadIdx.x;
    int qi = tid >> 5;
    int j8 = tid & 31;
    int q  = i0 + qi;

    __shared__ unsigned smax[256];
    smax[tid] = 0x007FFFFFu;      // umap(-inf)
    __syncthreads();

    if (q < nS) {
        float m = -1e30f;
#pragma unroll
        for (int cc = 0; cc < KS; ++cc)
            m = fmaxf(m, pml[((size_t)cc*N_CODE + q)*2 + 0]);
        float e[KS]; float l = 0.f;
#pragma unroll
        for (int cc = 0; cc < KS; ++cc) {
            e[cc] = __expf(pml[((size_t)cc*N_CODE + q)*2 + 0] - m);
            l += pml[((size_t)cc*N_CODE + q)*2 + 1] * e[cc];
        }
        float acc[8] = {};
#pragma unroll
        for (int cc = 0; cc < KS; ++cc) {
            bf16x8 v = *(const bf16x8*)(pO + ((size_t)cc*N_CODE + q)*256 + j8*8);
#pragma unroll
            for (int k = 0; k < 8; ++k) acc[k] += (float)v[k] * e[cc];
        }
        float linv = 1.f / fmaxf(l, 1e-30f);
        f32x4 o0, o1;
#pragma unroll
        for (int k = 0; k < 8; ++k) {
            float val = tanhf(acc[k] * linv);
            if (k < 4) o0[k] = val; else o1[k-4] = val;
            atomicMax(&smax[j8*8 + k], umap_f(val));   // LDS atomic (block-local)
        }
        float* dst = h_new + (size_t)idxS[q]*256 + j8*8;
        *(f32x4*)dst = o0;
        *(f32x4*)(dst + 4) = o1;
    }
    __syncthreads();
    atomicMax(&u23[tid], smax[tid]);   // one global atomic per column per block
}

__global__ void tl_final(const unsigned* __restrict__ u1, const unsigned* __restrict__ u23,
                         float* __restrict__ out)
{
    int d = threadIdx.x;
    out[d] = fmaxf(unmap_f(u1[d]), unmap_f(u23[d]));
}

extern "C" void kernel_launch(void* const* d_in, const int* in_sizes, int n_in,
                              void* d_out, int out_size, void* d_ws, size_t ws_size,
                              hipStream_t stream) {
    const float* m_emb  = (const float*)d_in[0];
    const float* ddi    = (const float*)d_in[1];
    const float* unrel  = (const float*)d_in[2];
    const float* hidden = (const float*)d_in[3];
    const float* W_ih   = (const float*)d_in[4];
    const float* W_hh   = (const float*)d_in[5];
    const float* b_ih   = (const float*)d_in[6];
    const float* b_hh   = (const float*)d_in[7];
    const float* Wq     = (const float*)d_in[8];
    const float* bq     = (const float*)d_in[9];
    const float* Wk     = (const float*)d_in[10];
    const float* bk     = (const float*)d_in[11];
    const float* Wv     = (const float*)d_in[12];
    const float* bv     = (const float*)d_in[13];
    const int*   divided= (const int*)d_in[14];

    char* ws = (char*)d_ws;
    bf16_t* B1p   = (bf16_t*)(ws + OFF_B1);
    bf16_t* B2p   = (bf16_t*)(ws + OFF_B2);
    bf16_t* B3p   = (bf16_t*)(ws + OFF_B3);
    bf16_t* BVp   = (bf16_t*)(ws + OFF_BV);
    float*  biases= (float*)(ws + OFF_BIAS);
    unsigned* u1  = (unsigned*)(ws + OFF_U1);
    unsigned* u23 = (unsigned*)(ws + OFF_U23);
    int*    counts= (int*)(ws + OFF_CNT);
    int*    idxS  = (int*)(ws + OFF_IDXS);
    int*    idxM1 = (int*)(ws + OFF_IDXM);
    bf16_t* gxc   = (bf16_t*)(ws + OFF_GXC);
    bf16_t* ghc   = (bf16_t*)(ws + OFF_GHC);
    bf16_t* G3c   = (bf16_t*)(ws + OFF_G3C);
    bf16_t* Vt    = (bf16_t*)(ws + OFF_VT);
    bf16_t* Kp    = (bf16_t*)(ws + OFF_KP);
    bf16_t* Vp    = (bf16_t*)(ws + OFF_VP);
    float*  pml   = (float*)(ws + OFF_PML);
    bf16_t* pO    = (bf16_t*)(ws + OFF_PO);

    // ksplit=8 is the measured optimum (round 15: 16 was neutral-negative)
    int ksplit;
    if (ws_size >= OFF_PO + (size_t)8 * 4194304)      ksplit = 8;
    else if (ws_size >= OFF_PO + (size_t)4 * 4194304) ksplit = 4;
    else                                              ksplit = 2;

    float* out   = (float*)d_out;
    float* h_new = out + 256;

    tl_prep_scan<<<dim3(129), dim3(1024), 0, stream>>>(W_ih, W_hh, Wq, Wk, Wv, b_ih, b_hh, bq, bk, bv,
                                                       divided, B1p, B2p, B3p, BVp, biases, u1, u23,
                                                       idxS, idxM1, counts);
    tl_gemm_quad<<<dim3(128, 8), dim3(256), 0, stream>>>(m_emb, hidden, ddi, unrel, divided,
                                                         B1p, B2p, B3p, BVp, biases,
                                                         gxc, ghc, G3c, Vt, idxM1, idxS, counts);
    tl_gru_pack<<<dim3(3072), dim3(256), 0, stream>>>(gxc, ghc, hidden, idxM1, counts, h_new, u1,
                                                      G3c, Vt, Kp, Vp);
    tl_attn<<<dim3(ksplit, 128), dim3(256), 0, stream>>>(G3c, Kp, Vp, counts, ksplit, pml, pO);
    if (ksplit == 8)      tl_merge_t<8><<<dim3(1024), dim3(256), 0, stream>>>(pO, pml, idxS, counts, h_new, u23);
    else if (ksplit == 4) tl_merge_t<4><<<dim3(1024), dim3(256), 0, stream>>>(pO, pml, idxS, counts, h_new, u23);
    else                  tl_merge_t<2><<<dim3(1024), dim3(256), 0, stream>>>(pO, pml, idxS, counts, h_new, u23);
    tl_final<<<dim3(1), dim3(256), 0, stream>>>(u1, u23, out);
}